// Round 5
// baseline (244.515 us; speedup 1.0000x reference)
//
#include <hip/hip_runtime.h>
#include <stdint.h>
#include <stddef.h>

#define IN_F   1024
#define OUT_F  1024
#define NROWS  16384
#define NTERMS 10

typedef __bf16 bf16x8 __attribute__((ext_vector_type(8)));
typedef float  f32x4  __attribute__((ext_vector_type(4)));
typedef unsigned short u16x8 __attribute__((ext_vector_type(8)));

union V8 { u16x8 u; bf16x8 b; };

__device__ __forceinline__ unsigned short f2bf(float f) {
    unsigned int u = __float_as_uint(f);
    unsigned int r = (u + 0x7FFFu + ((u >> 16) & 1u)) >> 16;
    return (unsigned short)r;
}

// ---------------------------------------------------------------- cast x -> bf16
__global__ void cast_x_kernel(const float* __restrict__ x, unsigned short* __restrict__ xb) {
    size_t i = ((size_t)blockIdx.x * 256 + threadIdx.x) * 8;
    float4 a = *(const float4*)(x + i);
    float4 b = *(const float4*)(x + i + 4);
    u16x8 o;
    o[0] = f2bf(a.x); o[1] = f2bf(a.y); o[2] = f2bf(a.z); o[3] = f2bf(a.w);
    o[4] = f2bf(b.x); o[5] = f2bf(b.y); o[6] = f2bf(b.z); o[7] = f2bf(b.w);
    *(u16x8*)(xb + i) = o;
}

// ------------------------------------------- base W -> bf16 ; mean spline W -> bf16
__global__ __launch_bounds__(256)
void prep_w_kernel(const float* __restrict__ bw, const float* __restrict__ sw,
                   unsigned short* __restrict__ wb, unsigned short* __restrict__ wm) {
    __shared__ float s[256 * NTERMS];
    const int tid = threadIdx.x;
    const size_t base = (size_t)blockIdx.x * 256;
    const float4* src = (const float4*)(sw + base * NTERMS);
#pragma unroll
    for (int it = 0; it < 3; ++it) {
        int j = tid + it * 256;
        if (j < (256 * NTERMS) / 4) ((float4*)s)[j] = src[j];
    }
    __syncthreads();
    float sum = 0.f;
#pragma unroll
    for (int t = 0; t < NTERMS; ++t) sum += s[tid * NTERMS + t];
    size_t i = base + tid;
    wm[i] = f2bf(sum * 0.1f);
    wb[i] = f2bf(bw[i]);
}

// ---------------------------------------------------------------- fused dual GEMM
// out[m][n] = silu( sum_k x[m][k]*Wb[n][k] ) + sum_k x[m][k]*Wm[n][k]
//
// ROUND-5: round-0 proven structure (2-barrier m97 K-loop, 16x16x32, 128x128
// tile, 4 waves, XOR bank swizzle — 70.1 µs, 0 conflicts), with ONE change:
// Wm (spline-mean weights, 2 MB, L2-resident) is no longer staged through
// LDS. Its fragments are loaded global->register at the top of each compute
// phase and consumed by the trailing s=1 MFMAs of each ksub (~150-200 cyc of
// MFMA/ds_read cover vs ~200 cyc L2 hit latency; 3 blocks/CU co-resident).
//   - LDS 48 KB -> 32 KB (As + Wb only)
//   - global_load_lds per thread per K-step: 12 -> 8 (smaller pre-barrier drain)
//   - LDS b128 reads per wave per K-step: 24 -> 16 (pipe demand below MFMA)
// Numerics identical to round-0 (same values, same accumulation order).
#define GLL16(GP, LP) __builtin_amdgcn_global_load_lds( \
    (const __attribute__((address_space(1))) unsigned int*)(GP), \
    (__attribute__((address_space(3))) unsigned int*)(LP), 16, 0, 0)

__global__ __launch_bounds__(256, 2)
void kan_gemm(const unsigned short* __restrict__ xb,
              const unsigned short* __restrict__ wbq,
              const unsigned short* __restrict__ wmq,
              float* __restrict__ out)
{
    __shared__ __align__(16) unsigned short As[128 * 64];
    __shared__ __align__(16) unsigned short Bs[128 * 64];

    const int tid  = threadIdx.x;
    const int lane = tid & 63;
    const int wave = tid >> 6;
    const int wm_  = wave >> 1;      // m half
    const int wn_  = wave & 1;       // n half
    const int rowl = lane & 15;
    const int quad = lane >> 4;

    const int m0 = blockIdx.x * 128;
    const int n0 = blockIdx.y * 128;

    f32x4 acc[2][4][4];
#pragma unroll
    for (int s = 0; s < 2; ++s)
#pragma unroll
        for (int mt = 0; mt < 4; ++mt)
#pragma unroll
            for (int nt = 0; nt < 4; ++nt)
                acc[s][mt][nt] = (f32x4){0.f, 0.f, 0.f, 0.f};

    // staging: 1024 chunks (16 B) per 128x64 tile, 4 per thread per tile
    int srow[4], sgc[4];   // row, swizzled global chunk
#pragma unroll
    for (int j = 0; j < 4; ++j) {
        int q = tid + j * 256;
        int r = q >> 3, cd = q & 7;
        srow[j] = r;
        sgc[j] = cd ^ (r & 7);
    }

    // Wm fragment base for this lane (linear global layout, no swizzle):
    // frag (ksub, nt): row = n0 + wn_*64 + nt*16 + rowl, k = k0 + (ksub*4+quad)*8
    const unsigned short* gml =
        wmq + (size_t)(n0 + wn_ * 64 + rowl) * IN_F + quad * 8;

    for (int k0 = 0; k0 < IN_F; k0 += 64) {
        __syncthreads();
#pragma unroll
        for (int j = 0; j < 4; ++j) {
            int q = tid + j * 256;
            const unsigned short* ga = xb + (size_t)(m0 + srow[j]) * IN_F + k0 + sgc[j] * 8;
            GLL16(ga, As + q * 8);
            const unsigned short* gb = wbq + (size_t)(n0 + srow[j]) * IN_F + k0 + sgc[j] * 8;
            GLL16(gb, Bs + q * 8);
        }
        __syncthreads();

        // issue all Wm fragment loads for this K-step (L2-resident; consumed
        // by the s=1 MFMAs below, giving the loads MFMA time to land)
        V8 gm[2][4];
#pragma unroll
        for (int ks = 0; ks < 2; ++ks)
#pragma unroll
            for (int nt = 0; nt < 4; ++nt)
                gm[ks][nt].u = *(const u16x8*)(gml + k0 + ks * 32 + (size_t)nt * 16 * IN_F);

#pragma unroll
        for (int ksub = 0; ksub < 2; ++ksub) {
            bf16x8 afrag[4], bfrag[4];
#pragma unroll
            for (int mt = 0; mt < 4; ++mt) {
                int r = wm_ * 64 + mt * 16 + rowl;
                int c = (ksub * 4 + quad) ^ (r & 7);
                union V8 t;
                t.u = *(const u16x8*)(As + r * 64 + c * 8);
                afrag[mt] = t.b;
            }
#pragma unroll
            for (int nt = 0; nt < 4; ++nt) {
                int r = wn_ * 64 + nt * 16 + rowl;
                int c = (ksub * 4 + quad) ^ (r & 7);
                union V8 t;
                t.u = *(const u16x8*)(Bs + r * 64 + c * 8);
                bfrag[nt] = t.b;
            }
            // base-path MFMAs first (LDS operands), spline-path second
            // (global-loaded operands -> extra latency cover)
#pragma unroll
            for (int mt = 0; mt < 4; ++mt)
#pragma unroll
                for (int nt = 0; nt < 4; ++nt)
                    acc[0][mt][nt] = __builtin_amdgcn_mfma_f32_16x16x32_bf16(
                        afrag[mt], bfrag[nt], acc[0][mt][nt], 0, 0, 0);
#pragma unroll
            for (int mt = 0; mt < 4; ++mt)
#pragma unroll
                for (int nt = 0; nt < 4; ++nt)
                    acc[1][mt][nt] = __builtin_amdgcn_mfma_f32_16x16x32_bf16(
                        afrag[mt], gm[ksub][nt].b, acc[1][mt][nt], 0, 0, 0);
        }
    }

    // epilogue: silu(base) + spline, fp32 store
    // C/D layout (16x16x32): col = lane&15, row = quad*4 + reg
#pragma unroll
    for (int mt = 0; mt < 4; ++mt)
#pragma unroll
        for (int nt = 0; nt < 4; ++nt)
#pragma unroll
            for (int r = 0; r < 4; ++r) {
                float vb = acc[0][mt][nt][r];
                float vm = acc[1][mt][nt][r];
                float o  = vb / (1.0f + __expf(-vb)) + vm;
                int row = m0 + wm_ * 64 + mt * 16 + quad * 4 + r;
                int col = n0 + wn_ * 64 + nt * 16 + rowl;
                out[(size_t)row * OUT_F + col] = o;
            }
}

extern "C" void kernel_launch(void* const* d_in, const int* in_sizes, int n_in,
                              void* d_out, int out_size, void* d_ws, size_t ws_size,
                              hipStream_t stream) {
    const float* x  = (const float*)d_in[0];   // [16384,1024]
    const float* bw = (const float*)d_in[1];   // [1024,1024]
    const float* sw = (const float*)d_in[2];   // [1024,1024,10]
    float* out = (float*)d_out;                // [16384,1024]

    unsigned short* xb  = (unsigned short*)d_ws;
    unsigned short* wbq = xb + (size_t)NROWS * IN_F;
    unsigned short* wmq = wbq + (size_t)OUT_F * IN_F;

    cast_x_kernel<<<dim3((NROWS * IN_F) / (256 * 8)), dim3(256), 0, stream>>>(x, xb);
    prep_w_kernel<<<dim3((OUT_F * IN_F) / 256), dim3(256), 0, stream>>>(bw, sw, wbq, wmq);
    kan_gemm<<<dim3(NROWS / 128, OUT_F / 128), dim3(256), 0, stream>>>(xb, wbq, wmq, out);
}

// Round 6
// 213.846 us; speedup vs baseline: 1.1434x; 1.1434x over previous
//
#include <hip/hip_runtime.h>
#include <stdint.h>
#include <stddef.h>

#define IN_F   1024
#define OUT_F  1024
#define NROWS  16384
#define NTERMS 10

#define CAST_BLOCKS ((NROWS * IN_F) / (256 * 8))   // 8192
#define PREP_BLOCKS ((OUT_F * IN_F) / 256)         // 4096

typedef __bf16 bf16x8 __attribute__((ext_vector_type(8)));
typedef float  f32x4  __attribute__((ext_vector_type(4)));
typedef unsigned short u16x8 __attribute__((ext_vector_type(8)));

union V8 { u16x8 u; bf16x8 b; };

__device__ __forceinline__ unsigned short f2bf(float f) {
    unsigned int u = __float_as_uint(f);
    unsigned int r = (u + 0x7FFFu + ((u >> 16) & 1u)) >> 16;
    return (unsigned short)r;
}

// ---------------------------------------------------- fused prep: cast x + weights
// blocks [0, CAST_BLOCKS)            : x fp32 -> bf16 (8 elems/thread)
// blocks [CAST_BLOCKS, +PREP_BLOCKS) : base W -> bf16 ; mean spline W -> bf16
__global__ __launch_bounds__(256)
void prep_all_kernel(const float* __restrict__ x, unsigned short* __restrict__ xb,
                     const float* __restrict__ bw, const float* __restrict__ sw,
                     unsigned short* __restrict__ wb, unsigned short* __restrict__ wm) {
    __shared__ float s[256 * NTERMS];
    const int tid = threadIdx.x;

    if (blockIdx.x < CAST_BLOCKS) {
        size_t i = ((size_t)blockIdx.x * 256 + tid) * 8;
        float4 a = *(const float4*)(x + i);
        float4 b = *(const float4*)(x + i + 4);
        u16x8 o;
        o[0] = f2bf(a.x); o[1] = f2bf(a.y); o[2] = f2bf(a.z); o[3] = f2bf(a.w);
        o[4] = f2bf(b.x); o[5] = f2bf(b.y); o[6] = f2bf(b.z); o[7] = f2bf(b.w);
        *(u16x8*)(xb + i) = o;
    } else {
        const size_t base = (size_t)(blockIdx.x - CAST_BLOCKS) * 256;
        const float4* src = (const float4*)(sw + base * NTERMS);
#pragma unroll
        for (int it = 0; it < 3; ++it) {
            int j = tid + it * 256;
            if (j < (256 * NTERMS) / 4) ((float4*)s)[j] = src[j];
        }
        __syncthreads();
        float sum = 0.f;
#pragma unroll
        for (int t = 0; t < NTERMS; ++t) sum += s[tid * NTERMS + t];
        size_t i = base + tid;
        wm[i] = f2bf(sum * 0.1f);
        wb[i] = f2bf(bw[i]);
    }
}

// ---------------------------------------------------------------- fused dual GEMM
// out[m][n] = silu( sum_k x[m][k]*Wb[n][k] ) + sum_k x[m][k]*Wm[n][k]
// 2-barrier m97 K-loop (proven best across 6 rounds), BK=64, XOR bank swizzle.
// Tile layout: rows of 64 bf16 (128 B = 8 chunks of 16 B). Chunk c of row r is
// stored at LDS chunk slot (c ^ (r&7)); the staging lanes fetch the permuted
// global chunk so LDS dest stays wavebase+lane*16 (global_load_lds constraint).
//
// Session ledger (do not re-try): 8-phase counted-vmcnt x3 (73/84/78 µs),
// 32x32x16 shape w/ extended swizzle (84 µs, 6.3M bank conflicts),
// Wm global->reg (106 µs). R0 structure = 70 µs, MfmaUtil 43.5%.
__global__ __launch_bounds__(256, 2)
void kan_gemm(const unsigned short* __restrict__ xb,
              const unsigned short* __restrict__ wbq,
              const unsigned short* __restrict__ wmq,
              float* __restrict__ out) {
    __shared__ __align__(16) unsigned short As[128 * 64];
    __shared__ __align__(16) unsigned short Bs[2][128 * 64];

    const int tid  = threadIdx.x;
    const int lane = tid & 63;
    const int wave = tid >> 6;
    const int wm_  = wave >> 1;      // m half
    const int wn_  = wave & 1;       // n half
    const int rowl = lane & 15;
    const int quad = lane >> 4;

    const int m0 = blockIdx.x * 128;
    const int n0 = blockIdx.y * 128;

    f32x4 acc[2][4][4];
#pragma unroll
    for (int s = 0; s < 2; ++s)
#pragma unroll
        for (int mt = 0; mt < 4; ++mt)
#pragma unroll
            for (int nt = 0; nt < 4; ++nt)
                acc[s][mt][nt] = (f32x4){0.f, 0.f, 0.f, 0.f};

    // staging: 1024 chunks (16 B) per 128x64 tile, 4 per thread per tile
    int srow[4], sgc[4];   // row, swizzled global chunk (same for all 3 tiles)
#pragma unroll
    for (int j = 0; j < 4; ++j) {
        int q = tid + j * 256;
        int r = q >> 3, cd = q & 7;
        srow[j] = r;
        sgc[j] = cd ^ (r & 7);
    }

    for (int k0 = 0; k0 < IN_F; k0 += 64) {
        __syncthreads();
#pragma unroll
        for (int j = 0; j < 4; ++j) {
            int q = tid + j * 256;
            const unsigned short* ga = xb + (size_t)(m0 + srow[j]) * IN_F + k0 + sgc[j] * 8;
            __builtin_amdgcn_global_load_lds(
                (const __attribute__((address_space(1))) unsigned int*)ga,
                (__attribute__((address_space(3))) unsigned int*)(As + q * 8), 16, 0, 0);
            const unsigned short* gb = wbq + (size_t)(n0 + srow[j]) * IN_F + k0 + sgc[j] * 8;
            __builtin_amdgcn_global_load_lds(
                (const __attribute__((address_space(1))) unsigned int*)gb,
                (__attribute__((address_space(3))) unsigned int*)(Bs[0] + q * 8), 16, 0, 0);
            const unsigned short* gm = wmq + (size_t)(n0 + srow[j]) * IN_F + k0 + sgc[j] * 8;
            __builtin_amdgcn_global_load_lds(
                (const __attribute__((address_space(1))) unsigned int*)gm,
                (__attribute__((address_space(3))) unsigned int*)(Bs[1] + q * 8), 16, 0, 0);
        }
        __syncthreads();

#pragma unroll
        for (int ksub = 0; ksub < 2; ++ksub) {
            bf16x8 afrag[4], bfrag[2][4];
#pragma unroll
            for (int mt = 0; mt < 4; ++mt) {
                int r = wm_ * 64 + mt * 16 + rowl;
                int c = (ksub * 4 + quad) ^ (r & 7);
                union V8 t;
                t.u = *(const u16x8*)(As + r * 64 + c * 8);
                afrag[mt] = t.b;
            }
#pragma unroll
            for (int s = 0; s < 2; ++s)
#pragma unroll
                for (int nt = 0; nt < 4; ++nt) {
                    int r = wn_ * 64 + nt * 16 + rowl;
                    int c = (ksub * 4 + quad) ^ (r & 7);
                    union V8 t;
                    t.u = *(const u16x8*)(Bs[s] + r * 64 + c * 8);
                    bfrag[s][nt] = t.b;
                }
#pragma unroll
            for (int s = 0; s < 2; ++s)
#pragma unroll
                for (int mt = 0; mt < 4; ++mt)
#pragma unroll
                    for (int nt = 0; nt < 4; ++nt)
                        acc[s][mt][nt] = __builtin_amdgcn_mfma_f32_16x16x32_bf16(
                            afrag[mt], bfrag[s][nt], acc[s][mt][nt], 0, 0, 0);
        }
    }

    // epilogue: silu(base) + spline, fp32 store
    // C/D layout (16x16x32): col = lane&15, row = quad*4 + reg
#pragma unroll
    for (int mt = 0; mt < 4; ++mt)
#pragma unroll
        for (int nt = 0; nt < 4; ++nt)
#pragma unroll
            for (int r = 0; r < 4; ++r) {
                float vb = acc[0][mt][nt][r];
                float vm = acc[1][mt][nt][r];
                float o  = vb / (1.0f + __expf(-vb)) + vm;
                int row = m0 + wm_ * 64 + mt * 16 + quad * 4 + r;
                int col = n0 + wn_ * 64 + nt * 16 + rowl;
                out[(size_t)row * OUT_F + col] = o;
            }
}

extern "C" void kernel_launch(void* const* d_in, const int* in_sizes, int n_in,
                              void* d_out, int out_size, void* d_ws, size_t ws_size,
                              hipStream_t stream) {
    const float* x  = (const float*)d_in[0];   // [16384,1024]
    const float* bw = (const float*)d_in[1];   // [1024,1024]
    const float* sw = (const float*)d_in[2];   // [1024,1024,10]
    float* out = (float*)d_out;                // [16384,1024]

    unsigned short* xb  = (unsigned short*)d_ws;
    unsigned short* wbq = xb + (size_t)NROWS * IN_F;
    unsigned short* wmq = wbq + (size_t)OUT_F * IN_F;

    prep_all_kernel<<<dim3(CAST_BLOCKS + PREP_BLOCKS), dim3(256), 0, stream>>>(
        x, xb, bw, sw, wbq, wmq);
    kan_gemm<<<dim3(NROWS / 128, OUT_F / 128), dim3(256), 0, stream>>>(xb, wbq, wmq, out);
}

// Round 7
// 211.299 us; speedup vs baseline: 1.1572x; 1.0121x over previous
//
#include <hip/hip_runtime.h>
#include <stdint.h>
#include <stddef.h>

#define IN_F   1024
#define OUT_F  1024
#define NROWS  16384
#define NTERMS 10

#define CAST_BLOCKS ((NROWS * IN_F) / (256 * 8))   // 8192
#define PREP_BLOCKS ((OUT_F * IN_F) / 256)         // 4096

typedef __bf16 bf16x8 __attribute__((ext_vector_type(8)));
typedef float  f32x4  __attribute__((ext_vector_type(4)));
typedef unsigned short u16x8 __attribute__((ext_vector_type(8)));

union V8 { u16x8 u; bf16x8 b; };

__device__ __forceinline__ unsigned short f2bf(float f) {
    unsigned int u = __float_as_uint(f);
    unsigned int r = (u + 0x7FFFu + ((u >> 16) & 1u)) >> 16;
    return (unsigned short)r;
}

// ---------------------------------------------------- fused prep: cast x + weights
// blocks [0, CAST_BLOCKS)            : x fp32 -> bf16 (8 elems/thread)
// blocks [CAST_BLOCKS, +PREP_BLOCKS) : base W -> bf16 ; mean spline W -> bf16
__global__ __launch_bounds__(256)
void prep_all_kernel(const float* __restrict__ x, unsigned short* __restrict__ xb,
                     const float* __restrict__ bw, const float* __restrict__ sw,
                     unsigned short* __restrict__ wb, unsigned short* __restrict__ wm) {
    __shared__ float s[256 * NTERMS];
    const int tid = threadIdx.x;

    if (blockIdx.x < CAST_BLOCKS) {
        size_t i = ((size_t)blockIdx.x * 256 + tid) * 8;
        float4 a = *(const float4*)(x + i);
        float4 b = *(const float4*)(x + i + 4);
        u16x8 o;
        o[0] = f2bf(a.x); o[1] = f2bf(a.y); o[2] = f2bf(a.z); o[3] = f2bf(a.w);
        o[4] = f2bf(b.x); o[5] = f2bf(b.y); o[6] = f2bf(b.z); o[7] = f2bf(b.w);
        *(u16x8*)(xb + i) = o;
    } else {
        const size_t base = (size_t)(blockIdx.x - CAST_BLOCKS) * 256;
        const float4* src = (const float4*)(sw + base * NTERMS);
#pragma unroll
        for (int it = 0; it < 3; ++it) {
            int j = tid + it * 256;
            if (j < (256 * NTERMS) / 4) ((float4*)s)[j] = src[j];
        }
        __syncthreads();
        float sum = 0.f;
#pragma unroll
        for (int t = 0; t < NTERMS; ++t) sum += s[tid * NTERMS + t];
        size_t i = base + tid;
        wm[i] = f2bf(sum * 0.1f);
        wb[i] = f2bf(bw[i]);
    }
}

// ---------------------------------------------------------------- fused dual GEMM
// out[m][n] = silu( sum_k x[m][k]*Wb[n][k] ) + sum_k x[m][k]*Wm[n][k]
// 2-barrier m97 K-loop (proven best across 7 rounds), BK=64, XOR bank swizzle.
// Tile layout: rows of 64 bf16 (128 B = 8 chunks of 16 B). Chunk c of row r is
// stored at LDS chunk slot (c ^ (r&7)); the staging lanes fetch the permuted
// global chunk so LDS dest stays wavebase+lane*16 (global_load_lds constraint).
//
// ROUND-7 CHANGE: output stores are NON-TEMPORAL. out is 65 MB write-once,
// never re-read; streaming it through L2 evicts the staging working set
// (A-panels ~4MB/XCD + B 4MB, already a marginal L2 fit) and causes re-fetch
// on the staging path (the kernel's actual bottleneck: transfer ~= compute
// per K-step with only 2 resident blocks). NT stores leave L2 to operands.
//
// Session ledger (do not re-try): 8-phase counted-vmcnt x3 (73/84/78 µs),
// 32x32x16 shape w/ extended swizzle (84 µs, 6.3M bank conflicts),
// Wm global->reg (106 µs). R6 structure = 68 µs. Occupancy is register-bound:
// 128 AGPR acc + ~104 VGPR = 232 unified regs -> 2 waves/SIMD -> 2 blocks/CU.
__global__ __launch_bounds__(256, 2)
void kan_gemm(const unsigned short* __restrict__ xb,
              const unsigned short* __restrict__ wbq,
              const unsigned short* __restrict__ wmq,
              float* __restrict__ out) {
    __shared__ __align__(16) unsigned short As[128 * 64];
    __shared__ __align__(16) unsigned short Bs[2][128 * 64];

    const int tid  = threadIdx.x;
    const int lane = tid & 63;
    const int wave = tid >> 6;
    const int wm_  = wave >> 1;      // m half
    const int wn_  = wave & 1;       // n half
    const int rowl = lane & 15;
    const int quad = lane >> 4;

    const int m0 = blockIdx.x * 128;
    const int n0 = blockIdx.y * 128;

    f32x4 acc[2][4][4];
#pragma unroll
    for (int s = 0; s < 2; ++s)
#pragma unroll
        for (int mt = 0; mt < 4; ++mt)
#pragma unroll
            for (int nt = 0; nt < 4; ++nt)
                acc[s][mt][nt] = (f32x4){0.f, 0.f, 0.f, 0.f};

    // staging: 1024 chunks (16 B) per 128x64 tile, 4 per thread per tile
    int srow[4], sgc[4];   // row, swizzled global chunk (same for all 3 tiles)
#pragma unroll
    for (int j = 0; j < 4; ++j) {
        int q = tid + j * 256;
        int r = q >> 3, cd = q & 7;
        srow[j] = r;
        sgc[j] = cd ^ (r & 7);
    }

    for (int k0 = 0; k0 < IN_F; k0 += 64) {
        __syncthreads();
#pragma unroll
        for (int j = 0; j < 4; ++j) {
            int q = tid + j * 256;
            const unsigned short* ga = xb + (size_t)(m0 + srow[j]) * IN_F + k0 + sgc[j] * 8;
            __builtin_amdgcn_global_load_lds(
                (const __attribute__((address_space(1))) unsigned int*)ga,
                (__attribute__((address_space(3))) unsigned int*)(As + q * 8), 16, 0, 0);
            const unsigned short* gb = wbq + (size_t)(n0 + srow[j]) * IN_F + k0 + sgc[j] * 8;
            __builtin_amdgcn_global_load_lds(
                (const __attribute__((address_space(1))) unsigned int*)gb,
                (__attribute__((address_space(3))) unsigned int*)(Bs[0] + q * 8), 16, 0, 0);
            const unsigned short* gm = wmq + (size_t)(n0 + srow[j]) * IN_F + k0 + sgc[j] * 8;
            __builtin_amdgcn_global_load_lds(
                (const __attribute__((address_space(1))) unsigned int*)gm,
                (__attribute__((address_space(3))) unsigned int*)(Bs[1] + q * 8), 16, 0, 0);
        }
        __syncthreads();

#pragma unroll
        for (int ksub = 0; ksub < 2; ++ksub) {
            bf16x8 afrag[4], bfrag[2][4];
#pragma unroll
            for (int mt = 0; mt < 4; ++mt) {
                int r = wm_ * 64 + mt * 16 + rowl;
                int c = (ksub * 4 + quad) ^ (r & 7);
                union V8 t;
                t.u = *(const u16x8*)(As + r * 64 + c * 8);
                afrag[mt] = t.b;
            }
#pragma unroll
            for (int s = 0; s < 2; ++s)
#pragma unroll
                for (int nt = 0; nt < 4; ++nt) {
                    int r = wn_ * 64 + nt * 16 + rowl;
                    int c = (ksub * 4 + quad) ^ (r & 7);
                    union V8 t;
                    t.u = *(const u16x8*)(Bs[s] + r * 64 + c * 8);
                    bfrag[s][nt] = t.b;
                }
#pragma unroll
            for (int s = 0; s < 2; ++s)
#pragma unroll
                for (int mt = 0; mt < 4; ++mt)
#pragma unroll
                    for (int nt = 0; nt < 4; ++nt)
                        acc[s][mt][nt] = __builtin_amdgcn_mfma_f32_16x16x32_bf16(
                            afrag[mt], bfrag[s][nt], acc[s][mt][nt], 0, 0, 0);
        }
    }

    // epilogue: silu(base) + spline, non-temporal fp32 store (out is write-once;
    // keep L2 for the staging operands)
    // C/D layout (16x16x32): col = lane&15, row = quad*4 + reg
#pragma unroll
    for (int mt = 0; mt < 4; ++mt)
#pragma unroll
        for (int nt = 0; nt < 4; ++nt)
#pragma unroll
            for (int r = 0; r < 4; ++r) {
                float vb = acc[0][mt][nt][r];
                float vm = acc[1][mt][nt][r];
                float o  = vb / (1.0f + __expf(-vb)) + vm;
                int row = m0 + wm_ * 64 + mt * 16 + quad * 4 + r;
                int col = n0 + wn_ * 64 + nt * 16 + rowl;
                __builtin_nontemporal_store(o, &out[(size_t)row * OUT_F + col]);
            }
}

extern "C" void kernel_launch(void* const* d_in, const int* in_sizes, int n_in,
                              void* d_out, int out_size, void* d_ws, size_t ws_size,
                              hipStream_t stream) {
    const float* x  = (const float*)d_in[0];   // [16384,1024]
    const float* bw = (const float*)d_in[1];   // [1024,1024]
    const float* sw = (const float*)d_in[2];   // [1024,1024,10]
    float* out = (float*)d_out;                // [16384,1024]

    unsigned short* xb  = (unsigned short*)d_ws;
    unsigned short* wbq = xb + (size_t)NROWS * IN_F;
    unsigned short* wmq = wbq + (size_t)OUT_F * IN_F;

    prep_all_kernel<<<dim3(CAST_BLOCKS + PREP_BLOCKS), dim3(256), 0, stream>>>(
        x, xb, bw, sw, wbq, wmq);
    kan_gemm<<<dim3(NROWS / 128, OUT_F / 128), dim3(256), 0, stream>>>(xb, wbq, wmq, out);
}

// Round 8
// 209.557 us; speedup vs baseline: 1.1668x; 1.0083x over previous
//
#include <hip/hip_runtime.h>
#include <stdint.h>
#include <stddef.h>

#define IN_F   1024
#define OUT_F  1024
#define NROWS  16384
#define NTERMS 10

#define CAST_BLOCKS ((NROWS * IN_F) / (256 * 8))   // 8192
#define PREP_BLOCKS ((OUT_F * IN_F) / 256)         // 4096

typedef __bf16 bf16x8 __attribute__((ext_vector_type(8)));
typedef float  f32x4  __attribute__((ext_vector_type(4)));
typedef unsigned short u16x8 __attribute__((ext_vector_type(8)));

union V8 { u16x8 u; bf16x8 b; };

__device__ __forceinline__ unsigned short f2bf(float f) {
    unsigned int u = __float_as_uint(f);
    unsigned int r = (u + 0x7FFFu + ((u >> 16) & 1u)) >> 16;
    return (unsigned short)r;
}

// ---------------------------------------------------- fused prep: cast x + weights
// blocks [0, CAST_BLOCKS)            : x fp32 -> bf16 (8 elems/thread)
// blocks [CAST_BLOCKS, +PREP_BLOCKS) : base W -> bf16 ; mean spline W -> bf16
__global__ __launch_bounds__(256)
void prep_all_kernel(const float* __restrict__ x, unsigned short* __restrict__ xb,
                     const float* __restrict__ bw, const float* __restrict__ sw,
                     unsigned short* __restrict__ wb, unsigned short* __restrict__ wm) {
    __shared__ float s[256 * NTERMS];
    const int tid = threadIdx.x;

    if (blockIdx.x < CAST_BLOCKS) {
        size_t i = ((size_t)blockIdx.x * 256 + tid) * 8;
        float4 a = *(const float4*)(x + i);
        float4 b = *(const float4*)(x + i + 4);
        u16x8 o;
        o[0] = f2bf(a.x); o[1] = f2bf(a.y); o[2] = f2bf(a.z); o[3] = f2bf(a.w);
        o[4] = f2bf(b.x); o[5] = f2bf(b.y); o[6] = f2bf(b.z); o[7] = f2bf(b.w);
        *(u16x8*)(xb + i) = o;
    } else {
        const size_t base = (size_t)(blockIdx.x - CAST_BLOCKS) * 256;
        const float4* src = (const float4*)(sw + base * NTERMS);
#pragma unroll
        for (int it = 0; it < 3; ++it) {
            int j = tid + it * 256;
            if (j < (256 * NTERMS) / 4) ((float4*)s)[j] = src[j];
        }
        __syncthreads();
        float sum = 0.f;
#pragma unroll
        for (int t = 0; t < NTERMS; ++t) sum += s[tid * NTERMS + t];
        size_t i = base + tid;
        wm[i] = f2bf(sum * 0.1f);
        wb[i] = f2bf(bw[i]);
    }
}

// ---------------------------------------------------------------- fused dual GEMM
// out[m][n] = silu( sum_k x[m][k]*Wb[n][k] ) + sum_k x[m][k]*Wm[n][k]
// 2-barrier m97 K-loop, BK=64, XOR bank swizzle. PROVEN BEST: 68.0 µs GEMM,
// MfmaUtil ~42%, FETCH 49.2 MB, WRITE 65.5 MB, bank conflicts 0.
// Tile layout: rows of 64 bf16 (128 B = 8 chunks of 16 B). Chunk c of row r is
// stored at LDS chunk slot (c ^ (r&7)); the staging lanes fetch the permuted
// global chunk so LDS dest stays wavebase+lane*16 (global_load_lds constraint).
//
// Session ledger — structural ceiling, do not re-try:
//   8-phase counted-vmcnt x3 variants    -> 73/84/78 µs (no 4-wave overlap)
//   32x32x16 shape + extended swizzle    -> 84 µs (6.3M bank conflicts)
//   Wm global->reg                       -> 106 µs (L2 latency on crit path)
//   non-temporal output stores           -> 81.5 µs (WRITE_SIZE +43%, no
//                                           L2 write-coalescing; FETCH unchanged
//                                           => no pollution benefit existed)
// Ceiling arithmetic: 2 blocks/CU (128 AGPR acc + ~104 VGPR), 48 KB staged +
// 24 ds_read_b128/wave + 32 MFMA/wave per K-step; pre-barrier vmcnt drain not
// hideable at this occupancy; every deeper pipeline measured slower.
__global__ __launch_bounds__(256, 2)
void kan_gemm(const unsigned short* __restrict__ xb,
              const unsigned short* __restrict__ wbq,
              const unsigned short* __restrict__ wmq,
              float* __restrict__ out) {
    __shared__ __align__(16) unsigned short As[128 * 64];
    __shared__ __align__(16) unsigned short Bs[2][128 * 64];

    const int tid  = threadIdx.x;
    const int lane = tid & 63;
    const int wave = tid >> 6;
    const int wm_  = wave >> 1;      // m half
    const int wn_  = wave & 1;       // n half
    const int rowl = lane & 15;
    const int quad = lane >> 4;

    const int m0 = blockIdx.x * 128;
    const int n0 = blockIdx.y * 128;

    f32x4 acc[2][4][4];
#pragma unroll
    for (int s = 0; s < 2; ++s)
#pragma unroll
        for (int mt = 0; mt < 4; ++mt)
#pragma unroll
            for (int nt = 0; nt < 4; ++nt)
                acc[s][mt][nt] = (f32x4){0.f, 0.f, 0.f, 0.f};

    // staging: 1024 chunks (16 B) per 128x64 tile, 4 per thread per tile
    int srow[4], sgc[4];   // row, swizzled global chunk (same for all 3 tiles)
#pragma unroll
    for (int j = 0; j < 4; ++j) {
        int q = tid + j * 256;
        int r = q >> 3, cd = q & 7;
        srow[j] = r;
        sgc[j] = cd ^ (r & 7);
    }

    for (int k0 = 0; k0 < IN_F; k0 += 64) {
        __syncthreads();
#pragma unroll
        for (int j = 0; j < 4; ++j) {
            int q = tid + j * 256;
            const unsigned short* ga = xb + (size_t)(m0 + srow[j]) * IN_F + k0 + sgc[j] * 8;
            __builtin_amdgcn_global_load_lds(
                (const __attribute__((address_space(1))) unsigned int*)ga,
                (__attribute__((address_space(3))) unsigned int*)(As + q * 8), 16, 0, 0);
            const unsigned short* gb = wbq + (size_t)(n0 + srow[j]) * IN_F + k0 + sgc[j] * 8;
            __builtin_amdgcn_global_load_lds(
                (const __attribute__((address_space(1))) unsigned int*)gb,
                (__attribute__((address_space(3))) unsigned int*)(Bs[0] + q * 8), 16, 0, 0);
            const unsigned short* gm = wmq + (size_t)(n0 + srow[j]) * IN_F + k0 + sgc[j] * 8;
            __builtin_amdgcn_global_load_lds(
                (const __attribute__((address_space(1))) unsigned int*)gm,
                (__attribute__((address_space(3))) unsigned int*)(Bs[1] + q * 8), 16, 0, 0);
        }
        __syncthreads();

#pragma unroll
        for (int ksub = 0; ksub < 2; ++ksub) {
            bf16x8 afrag[4], bfrag[2][4];
#pragma unroll
            for (int mt = 0; mt < 4; ++mt) {
                int r = wm_ * 64 + mt * 16 + rowl;
                int c = (ksub * 4 + quad) ^ (r & 7);
                union V8 t;
                t.u = *(const u16x8*)(As + r * 64 + c * 8);
                afrag[mt] = t.b;
            }
#pragma unroll
            for (int s = 0; s < 2; ++s)
#pragma unroll
                for (int nt = 0; nt < 4; ++nt) {
                    int r = wn_ * 64 + nt * 16 + rowl;
                    int c = (ksub * 4 + quad) ^ (r & 7);
                    union V8 t;
                    t.u = *(const u16x8*)(Bs[s] + r * 64 + c * 8);
                    bfrag[s][nt] = t.b;
                }
#pragma unroll
            for (int s = 0; s < 2; ++s)
#pragma unroll
                for (int mt = 0; mt < 4; ++mt)
#pragma unroll
                    for (int nt = 0; nt < 4; ++nt)
                        acc[s][mt][nt] = __builtin_amdgcn_mfma_f32_16x16x32_bf16(
                            afrag[mt], bfrag[s][nt], acc[s][mt][nt], 0, 0, 0);
        }
    }

    // epilogue: silu(base) + spline, fp32 store (plain stores: L2 write-
    // coalescing is required — NT stores amplified WRITE_SIZE by 43%)
    // C/D layout (16x16x32): col = lane&15, row = quad*4 + reg
#pragma unroll
    for (int mt = 0; mt < 4; ++mt)
#pragma unroll
        for (int nt = 0; nt < 4; ++nt)
#pragma unroll
            for (int r = 0; r < 4; ++r) {
                float vb = acc[0][mt][nt][r];
                float vm = acc[1][mt][nt][r];
                float o  = vb / (1.0f + __expf(-vb)) + vm;
                int row = m0 + wm_ * 64 + mt * 16 + quad * 4 + r;
                int col = n0 + wn_ * 64 + nt * 16 + rowl;
                out[(size_t)row * OUT_F + col] = o;
            }
}

extern "C" void kernel_launch(void* const* d_in, const int* in_sizes, int n_in,
                              void* d_out, int out_size, void* d_ws, size_t ws_size,
                              hipStream_t stream) {
    const float* x  = (const float*)d_in[0];   // [16384,1024]
    const float* bw = (const float*)d_in[1];   // [1024,1024]
    const float* sw = (const float*)d_in[2];   // [1024,1024,10]
    float* out = (float*)d_out;                // [16384,1024]

    unsigned short* xb  = (unsigned short*)d_ws;
    unsigned short* wbq = xb + (size_t)NROWS * IN_F;
    unsigned short* wmq = wbq + (size_t)OUT_F * IN_F;

    prep_all_kernel<<<dim3(CAST_BLOCKS + PREP_BLOCKS), dim3(256), 0, stream>>>(
        x, xb, bw, sw, wbq, wmq);
    kan_gemm<<<dim3(NROWS / 128, OUT_F / 128), dim3(256), 0, stream>>>(xb, wbq, wmq, out);
}